// Round 15
// baseline (168.900 us; speedup 1.0000x reference)
//
#include <hip/hip_runtime.h>

// Problem: B=32, N=384, C=768, H=12, hd=64, scale=1/8, EPS=1e-6
#define BB 32
#define NN 384
#define CC 768
#define HH 12
#define HD 64

typedef __attribute__((ext_vector_type(4))) float f32x4;
typedef __attribute__((ext_vector_type(8))) __bf16 bf16x8;
typedef __attribute__((ext_vector_type(4))) __bf16 bf16x4;

static __device__ __forceinline__ f32x4 mfma16(bf16x8 a, bf16x8 b, f32x4 c) {
    return __builtin_amdgcn_mfma_f32_16x16x32_bf16(a, b, c, 0, 0, 0);
}

// async global->LDS DMA, 16B per lane. LDS dest is WAVE-UNIFORM base; HW adds lane*16.
static __device__ __forceinline__ void gload_lds16(const void* g, void* l) {
    __builtin_amdgcn_global_load_lds((const __attribute__((address_space(1))) void*)g,
                                     (__attribute__((address_space(3))) void*)l, 16, 0, 0);
}

// ---------------- fused f32 -> bf16 convert (all 3 sources, 1 launch) ------
#define XU   1179648   // x units (of 8 elem)
#define QU   73728     // qkv_w Q-part units
#define QKVU 221184    // qkv_w total units
#define PU   73728     // proj_w units
__global__ void cvt_kernel(const float* __restrict__ x, const float* __restrict__ qkv_w,
                           const float* __restrict__ proj_w, __bf16* __restrict__ dst) {
    const int i = blockIdx.x * blockDim.x + threadIdx.x;
    if (i >= XU + QKVU + PU) return;
    const float* src;
    float sc = 1.f;
    if (i < XU) src = x + (size_t)i * 8;
    else if (i < XU + QKVU) {
        src = qkv_w + (size_t)(i - XU) * 8;
        if (i < XU + QU) sc = 0.125f;  // Q weight rows pre-scaled by softmax scale
    } else src = proj_w + (size_t)(i - XU - QKVU) * 8;
    f32x4 a = *(const f32x4*)src;
    f32x4 b = *(const f32x4*)(src + 4);
    bf16x8 o;
#pragma unroll
    for (int j = 0; j < 4; ++j) { o[j] = (__bf16)(a[j] * sc); o[j + 4] = (__bf16)(b[j] * sc); }
    *(bf16x8*)(dst + (size_t)i * 8) = o;
}

// ---------------- GEMM: C[M][ncol] = A[M][768] * Bw[ncol][768]^T + bias ----
// 2-phase dbuf + both-sides XOR swizzle (conflicts=0); default dispatch order
// (XCD swizzle was wrong for this A-dominated shape, r13).
template <int EPI>
__global__ __launch_bounds__(256, 2) void gemm_kernel(
    const __bf16* __restrict__ A, const __bf16* __restrict__ Bw,
    const float* __restrict__ bias,
    __bf16* __restrict__ qkbuf, __bf16* __restrict__ vtbuf,
    float* __restrict__ fout) {
    __shared__ __bf16 SA[2][128 * 64];
    __shared__ __bf16 SB[2][128 * 64];

    const int tid = threadIdx.x;
    const int l = tid & 63;
    const int w = tid >> 6;
    const int g = l >> 4, q16 = l & 15;
    const int mb = blockIdx.x * 128;
    const int nb = blockIdx.y * 128;
    const int wrb = (w >> 1) * 64;
    const int wcb = (w & 1) * 64;
    const int swz = q16 & 7;  // frag-row & 7 == q16 & 7 (row bases are mult of 16)

    auto stage = [&](int buf, int kt) {
#pragma unroll
        for (int j = 0; j < 4; ++j) {
            const int ci = j * 256 + w * 64 + l;
            const int row = ci >> 3, c = ci & 7;
            const size_t go = (size_t)row * CC + kt * 64 + ((c ^ (row & 7)) << 3);
            gload_lds16(&A[(size_t)mb * CC + go], &SA[buf][(j * 256 + w * 64) * 8]);
            gload_lds16(&Bw[(size_t)nb * CC + go], &SB[buf][(j * 256 + w * 64) * 8]);
        }
    };

    f32x4 acc[4][4] = {};

    stage(0, 0);
    __syncthreads();  // tile 0 landed

    for (int kt = 0; kt < 12; ++kt) {
        const int buf = kt & 1;
        if (kt < 11) stage(buf ^ 1, kt + 1);  // prefetch overlaps compute below
        const char* pa = (const char*)&SA[buf][0];
        const char* pb = (const char*)&SB[buf][0];
#pragma unroll
        for (int c4 = 0; c4 < 2; ++c4) {
            bf16x8 af[4], bfr[4];
#pragma unroll
            for (int m = 0; m < 4; ++m)
                af[m] = *(const bf16x8*)(pa + (wrb + m * 16 + q16) * 128 +
                                         (((c4 * 4 + g) ^ swz) << 4));
#pragma unroll
            for (int n = 0; n < 4; ++n)
                bfr[n] = *(const bf16x8*)(pb + (wcb + n * 16 + q16) * 128 +
                                          (((c4 * 4 + g) ^ swz) << 4));
            __builtin_amdgcn_s_setprio(1);
#pragma unroll
            for (int m = 0; m < 4; ++m)
#pragma unroll
                for (int n = 0; n < 4; ++n)
                    acc[m][n] = mfma16(af[m], bfr[n], acc[m][n]);
            __builtin_amdgcn_s_setprio(0);
        }
        __syncthreads();  // drains prefetch (vmcnt) + reads (lgkm)
    }

    // epilogue. C/D layout: col = q16 (+16*n), row = 4*g + r (+16*m)
    if constexpr (EPI == 0) {
        const int bbatch = mb / NN;
        const int tokb = mb % NN;
#pragma unroll
        for (int n = 0; n < 4; ++n) {
            const int colb = nb + wcb + n * 16;
            const int col = colb + q16;
            float bs = bias[col];
            if (colb < 2 * CC) {
                if (colb < CC) bs *= 0.125f;
#pragma unroll
                for (int m = 0; m < 4; ++m) {
                    const int row = mb + wrb + m * 16 + g * 4;
#pragma unroll
                    for (int r = 0; r < 4; ++r)
                        qkbuf[(size_t)(row + r) * 1536 + col] = (__bf16)(acc[m][n][r] + bs);
                }
            } else {
                const int dd = (col - 2 * CC) & 63;
                const int hh = (colb - 2 * CC) >> 6;
                __bf16* vp = vtbuf + ((size_t)(bbatch * HH + hh) * HD + dd) * NN;
#pragma unroll
                for (int m = 0; m < 4; ++m) {
                    const int tok = tokb + wrb + m * 16 + g * 4;
                    bf16x4 pk;
#pragma unroll
                    for (int r = 0; r < 4; ++r) pk[r] = (__bf16)(acc[m][n][r] + bs);
                    *(bf16x4*)&vp[tok] = pk;
                }
            }
        }
    } else {
#pragma unroll
        for (int n = 0; n < 4; ++n) {
            const int col = nb + wcb + n * 16 + q16;
            const float bs = bias[col];
#pragma unroll
            for (int m = 0; m < 4; ++m)
#pragma unroll
                for (int r = 0; r < 4; ++r)
                    fout[(size_t)(mb + wrb + m * 16 + g * 4 + r) * CC + col] = acc[m][n][r] + bs;
        }
    }
}

// ---------------- fused policy-softmax attention (no-max, 2 blocks/CU) -----
// r12 structure with the launch-bounds fixed: ONE block per (b,h), grid 384,
// 512 threads. Only V (+pol) in LDS (49.5 KB -> 2 blocks/CU, 16 waves); Q/K
// read from global (block-local slabs -> L1/L2-hit; r12 FETCH was 30.6 MB).
// r12's (512,4) capped VGPR at 64 -> 44-VGPR zero-ILP kernel (80 us). Now
// (512,2): VGPR cap 128, hot state ~85 -> no spill, no strangle.
__global__ __launch_bounds__(512, 2) void attn_kernel(
    const __bf16* __restrict__ qkbuf, const __bf16* __restrict__ vtbuf,
    const float* __restrict__ policy, __bf16* __restrict__ attb) {
    __shared__ __bf16 Vlds[HD * NN];  // 48 KB, [row][768B], swz on 16B chunks
    __shared__ float pol[NN];

    const int tid = threadIdx.x;
    const int l = tid & 63;
    const int w = tid >> 6;
    const int g = l >> 4, q16 = l & 15;
    const int bh = blockIdx.x;
    const int b = bh / HH, h = bh % HH;

    const __bf16* vg = vtbuf + (size_t)(b * HH + h) * HD * NN;
#pragma unroll
    for (int p = 0; p < 6; ++p) {
        const int cs = p * 512 + w * 64 + l;
        const int row = cs / 48, cin = cs - row * 48;
        gload_lds16(&vg[row * NN + ((cin ^ (row & 7)) << 3)], &Vlds[(p * 512 + w * 64) * 8]);
    }
    for (int i = tid; i < NN; i += 512) pol[i] = policy[b * NN + i];
    __syncthreads();

    const int sw = (q16 & 7) << 4;
    const __bf16* qg0 = qkbuf + (size_t)b * NN * 1536 + h * HD;
    const __bf16* kg = qg0 + CC;

    // pack this thread's 96 policy-keep bits (key = kt*64 + t*16 + g*4 + r,
    // bit = kt*16 + t*4 + r) into 3 u32 -- built once, reused all 3 passes.
    unsigned kw0 = 0, kw1 = 0, kw2 = 0;
#pragma unroll
    for (int kt = 0; kt < 6; ++kt)
#pragma unroll
        for (int t = 0; t < 4; ++t)
#pragma unroll
            for (int r = 0; r < 4; ++r) {
                const int key = kt * 64 + t * 16 + g * 4 + r;
                const unsigned bset = (pol[key] > 0.5f) ? 1u : 0u;
                const int bit = kt * 16 + t * 4 + r;
                if (bit < 32) kw0 |= bset << bit;
                else if (bit < 64) kw1 |= bset << (bit - 32);
                else kw2 |= bset << (bit - 64);
            }

#pragma unroll 1
    for (int ps = 0; ps < 3; ++ps) {
        const int qrow = ps * 128 + w * 16 + q16;
        const __bf16* qg = qg0 + (size_t)qrow * 1536;
        const bf16x8 qf0 = *(const bf16x8*)&qg[g * 8];
        const bf16x8 qf1 = *(const bf16x8*)&qg[32 + g * 8];

        // per-pass mask: OR in the self-key bit (eye blend) if this thread owns it
        unsigned pw0 = kw0, pw1 = kw1, pw2 = kw2;
        if (((qrow >> 2) & 3) == g) {
            const int sbit = (qrow >> 6) * 16 + ((qrow >> 4) & 3) * 4 + (qrow & 3);
            if (sbit < 32) pw0 |= 1u << sbit;
            else if (sbit < 64) pw1 |= 1u << (sbit - 32);
            else pw2 |= 1u << (sbit - 64);
        }

        f32x4 oacc[4] = {};
        f32x4 ssum = {0.f, 0.f, 0.f, 0.f};

#pragma unroll 2
        for (int kt = 0; kt < 6; ++kt) {
            f32x4 st[4];
            __builtin_amdgcn_s_setprio(1);
#pragma unroll
            for (int t = 0; t < 4; ++t) {
                const __bf16* kr = &kg[(size_t)((kt * 4 + t) * 16 + q16) * 1536];
                bf16x8 k0 = *(const bf16x8*)&kr[g * 8];
                bf16x8 k1 = *(const bf16x8*)&kr[32 + g * 8];
                f32x4 z = {0.f, 0.f, 0.f, 0.f};
                st[t] = mfma16(k1, qf1, mfma16(k0, qf0, z));
            }
            __builtin_amdgcn_s_setprio(0);

            // e = keep ? exp(s) : 0  (no max subtraction; |s| <= ~2)
#pragma unroll
            for (int t = 0; t < 4; ++t) {
#pragma unroll
                for (int r = 0; r < 4; ++r) {
                    const int bit = kt * 16 + t * 4 + r;  // compile-time
                    const unsigned wsel = (bit < 32) ? pw0 : ((bit < 64) ? pw1 : pw2);
                    const bool keep = (wsel >> (bit & 31)) & 1u;
                    st[t][r] = keep ? __expf(st[t][r]) : 0.f;
                }
                ssum += st[t];
            }

            __builtin_amdgcn_s_setprio(1);
#pragma unroll
            for (int c4 = 0; c4 < 2; ++c4) {
                bf16x8 pf;
#pragma unroll
                for (int r = 0; r < 4; ++r) {
                    pf[r] = (__bf16)st[2 * c4][r];
                    pf[r + 4] = (__bf16)st[2 * c4 + 1][r];
                }
                const int c = kt * 2 + c4;
#pragma unroll
                for (int db = 0; db < 4; ++db) {
                    const int byte0 = (db * 16 + q16) * 768 + c * 64 + g * 8;
                    bf16x4 v0 = *(const bf16x4*)((const char*)Vlds + (byte0 ^ sw));
                    bf16x4 v1 = *(const bf16x4*)((const char*)Vlds + ((byte0 + 32) ^ sw));
                    bf16x8 vf;
#pragma unroll
                    for (int r = 0; r < 4; ++r) { vf[r] = v0[r]; vf[r + 4] = v1[r]; }
                    oacc[db] = mfma16(vf, pf, oacc[db]);
                }
            }
            __builtin_amdgcn_s_setprio(0);
        }

        float sum = (ssum[0] + ssum[1]) + (ssum[2] + ssum[3]);
        sum += __shfl_xor(sum, 16);
        sum += __shfl_xor(sum, 32);
        const float dinv = 1.f / (sum + 1e-6f);  // eps terms ~1e-6 rel: negligible

        __bf16* op = attb + ((size_t)b * NN + qrow) * CC + h * HD;
#pragma unroll
        for (int db = 0; db < 4; ++db) {
            bf16x4 pk;
#pragma unroll
            for (int r = 0; r < 4; ++r) pk[r] = (__bf16)(oacc[db][r] * dinv);
            *(bf16x4*)&op[db * 16 + g * 4] = pk;
        }
    }
}

extern "C" void kernel_launch(void* const* d_in, const int* in_sizes, int n_in,
                              void* d_out, int out_size, void* d_ws, size_t ws_size,
                              hipStream_t stream) {
    (void)in_sizes; (void)n_in; (void)out_size; (void)ws_size;
    const float* x      = (const float*)d_in[0];
    const float* policy = (const float*)d_in[1];
    const float* qkv_w  = (const float*)d_in[2];
    const float* qkv_b  = (const float*)d_in[3];
    const float* proj_w = (const float*)d_in[4];
    const float* proj_b = (const float*)d_in[5];
    float* out = (float*)d_out;

    // workspace layout (bf16), total ~94.5 MB
    __bf16* xb    = (__bf16*)d_ws;                     // 12288*768
    __bf16* wqkv  = xb + (size_t)12288 * 768;          // 2304*768
    __bf16* wproj = wqkv + (size_t)2304 * 768;         // 768*768
    __bf16* qkbuf = wproj + (size_t)768 * 768;         // 12288*1536 (Q|K)
    __bf16* vtbuf = qkbuf + (size_t)12288 * 1536;      // 32*12*64*384 (V^T)
    __bf16* attb  = vtbuf + (size_t)BB * HH * HD * NN; // 12288*768

    const int units = XU + QKVU + PU;
    cvt_kernel<<<(units + 255) / 256, 256, 0, stream>>>(x, qkv_w, proj_w, xb);

    gemm_kernel<0><<<dim3(96, 18), 256, 0, stream>>>(xb, wqkv, qkv_b, qkbuf, vtbuf, nullptr);
    attn_kernel<<<384, 512, 0, stream>>>(qkbuf, vtbuf, policy, attb);
    gemm_kernel<1><<<dim3(96, 6), 256, 0, stream>>>(attb, wproj, proj_b, nullptr, nullptr, out);
}

// Round 16
// 150.950 us; speedup vs baseline: 1.1189x; 1.1189x over previous
//
#include <hip/hip_runtime.h>

// Problem: B=32, N=384, C=768, H=12, hd=64, scale=1/8, EPS=1e-6
#define BB 32
#define NN 384
#define CC 768
#define HH 12
#define HD 64

typedef __attribute__((ext_vector_type(4))) float f32x4;
typedef __attribute__((ext_vector_type(8))) __bf16 bf16x8;
typedef __attribute__((ext_vector_type(4))) __bf16 bf16x4;

static __device__ __forceinline__ f32x4 mfma16(bf16x8 a, bf16x8 b, f32x4 c) {
    return __builtin_amdgcn_mfma_f32_16x16x32_bf16(a, b, c, 0, 0, 0);
}

// async global->LDS DMA, 16B per lane. LDS dest is WAVE-UNIFORM base; HW adds lane*16.
static __device__ __forceinline__ void gload_lds16(const void* g, void* l) {
    __builtin_amdgcn_global_load_lds((const __attribute__((address_space(1))) void*)g,
                                     (__attribute__((address_space(3))) void*)l, 16, 0, 0);
}

// ---------------- fused f32 -> bf16 convert (all 3 sources, 1 launch) ------
#define XU   1179648   // x units (of 8 elem)
#define QU   73728     // qkv_w Q-part units
#define QKVU 221184    // qkv_w total units
#define PU   73728     // proj_w units
__global__ void cvt_kernel(const float* __restrict__ x, const float* __restrict__ qkv_w,
                           const float* __restrict__ proj_w, __bf16* __restrict__ dst) {
    const int i = blockIdx.x * blockDim.x + threadIdx.x;
    if (i >= XU + QKVU + PU) return;
    const float* src;
    float sc = 1.f;
    if (i < XU) src = x + (size_t)i * 8;
    else if (i < XU + QKVU) {
        src = qkv_w + (size_t)(i - XU) * 8;
        if (i < XU + QU) sc = 0.125f;  // Q weight rows pre-scaled by softmax scale
    } else src = proj_w + (size_t)(i - XU - QKVU) * 8;
    f32x4 a = *(const f32x4*)src;
    f32x4 b = *(const f32x4*)(src + 4);
    bf16x8 o;
#pragma unroll
    for (int j = 0; j < 4; ++j) { o[j] = (__bf16)(a[j] * sc); o[j + 4] = (__bf16)(b[j] * sc); }
    *(bf16x8*)(dst + (size_t)i * 8) = o;
}

// ---------------- GEMM: C[M][ncol] = A[M][768] * Bw[ncol][768]^T + bias ----
// 2-phase dbuf + both-sides XOR swizzle (conflicts=0). NEW (T4): split the
// per-K-step __syncthreads into {vmcnt(8); s_barrier} pre-compute and
// {lgkmcnt(0); s_barrier} post-compute. r11's __syncthreads drained vmcnt(0)
// INCLUDING the same-iteration prefetch -> loads only got the compute phase
// (~350cy) to land. Now last-iter's loads age a full iteration before the
// wait, and this iter's prefetch stays in flight across both barriers.
template <int EPI>
__global__ __launch_bounds__(256, 2) void gemm_kernel(
    const __bf16* __restrict__ A, const __bf16* __restrict__ Bw,
    const float* __restrict__ bias,
    __bf16* __restrict__ qkbuf, __bf16* __restrict__ vtbuf,
    float* __restrict__ fout) {
    __shared__ __bf16 SA[2][128 * 64];
    __shared__ __bf16 SB[2][128 * 64];

    const int tid = threadIdx.x;
    const int l = tid & 63;
    const int w = tid >> 6;
    const int g = l >> 4, q16 = l & 15;
    const int mb = blockIdx.x * 128;
    const int nb = blockIdx.y * 128;
    const int wrb = (w >> 1) * 64;
    const int wcb = (w & 1) * 64;
    const int swz = q16 & 7;  // frag-row & 7 == q16 & 7 (row bases are mult of 16)

    auto stage = [&](int buf, int kt) {  // 8 vmem instrs per thread
#pragma unroll
        for (int j = 0; j < 4; ++j) {
            const int ci = j * 256 + w * 64 + l;
            const int row = ci >> 3, c = ci & 7;
            const size_t go = (size_t)row * CC + kt * 64 + ((c ^ (row & 7)) << 3);
            gload_lds16(&A[(size_t)mb * CC + go], &SA[buf][(j * 256 + w * 64) * 8]);
            gload_lds16(&Bw[(size_t)nb * CC + go], &SB[buf][(j * 256 + w * 64) * 8]);
        }
    };

    f32x4 acc[4][4] = {};

    stage(0, 0);  // 8 outstanding

    for (int kt = 0; kt < 12; ++kt) {
        const int buf = kt & 1;
        // issue next tile first (stays in flight across both barriers)
        if (kt < 11) {
            stage(buf ^ 1, kt + 1);                       // 16 outstanding
            asm volatile("s_waitcnt vmcnt(8)" ::: "memory");  // wait last-iter's 8
        } else {
            asm volatile("s_waitcnt vmcnt(0)" ::: "memory");  // tail: nothing new issued
        }
        __builtin_amdgcn_sched_barrier(0);
        asm volatile("s_barrier" ::: "memory");  // all waves: buf loads landed

        const char* pa = (const char*)&SA[buf][0];
        const char* pb = (const char*)&SB[buf][0];
#pragma unroll
        for (int c4 = 0; c4 < 2; ++c4) {
            bf16x8 af[4], bfr[4];
#pragma unroll
            for (int m = 0; m < 4; ++m)
                af[m] = *(const bf16x8*)(pa + (wrb + m * 16 + q16) * 128 +
                                         (((c4 * 4 + g) ^ swz) << 4));
#pragma unroll
            for (int n = 0; n < 4; ++n)
                bfr[n] = *(const bf16x8*)(pb + (wcb + n * 16 + q16) * 128 +
                                          (((c4 * 4 + g) ^ swz) << 4));
            __builtin_amdgcn_s_setprio(1);
#pragma unroll
            for (int m = 0; m < 4; ++m)
#pragma unroll
                for (int n = 0; n < 4; ++n)
                    acc[m][n] = mfma16(af[m], bfr[n], acc[m][n]);
            __builtin_amdgcn_s_setprio(0);
        }
        // release buf for next iter's DMA: my reads done, then block-wide rendezvous
        asm volatile("s_waitcnt lgkmcnt(0)" ::: "memory");
        __builtin_amdgcn_sched_barrier(0);
        asm volatile("s_barrier" ::: "memory");
    }

    // epilogue. C/D layout: col = q16 (+16*n), row = 4*g + r (+16*m)
    if constexpr (EPI == 0) {
        const int bbatch = mb / NN;
        const int tokb = mb % NN;
#pragma unroll
        for (int n = 0; n < 4; ++n) {
            const int colb = nb + wcb + n * 16;
            const int col = colb + q16;
            float bs = bias[col];
            if (colb < 2 * CC) {
                if (colb < CC) bs *= 0.125f;
#pragma unroll
                for (int m = 0; m < 4; ++m) {
                    const int row = mb + wrb + m * 16 + g * 4;
#pragma unroll
                    for (int r = 0; r < 4; ++r)
                        qkbuf[(size_t)(row + r) * 1536 + col] = (__bf16)(acc[m][n][r] + bs);
                }
            } else {
                const int dd = (col - 2 * CC) & 63;
                const int hh = (colb - 2 * CC) >> 6;
                __bf16* vp = vtbuf + ((size_t)(bbatch * HH + hh) * HD + dd) * NN;
#pragma unroll
                for (int m = 0; m < 4; ++m) {
                    const int tok = tokb + wrb + m * 16 + g * 4;
                    bf16x4 pk;
#pragma unroll
                    for (int r = 0; r < 4; ++r) pk[r] = (__bf16)(acc[m][n][r] + bs);
                    *(bf16x4*)&vp[tok] = pk;
                }
            }
        }
    } else {
#pragma unroll
        for (int n = 0; n < 4; ++n) {
            const int col = nb + wcb + n * 16 + q16;
            const float bs = bias[col];
#pragma unroll
            for (int m = 0; m < 4; ++m)
#pragma unroll
                for (int r = 0; r < 4; ++r)
                    fout[(size_t)(mb + wrb + m * 16 + g * 4 + r) * CC + col] = acc[m][n][r] + bs;
        }
    }
}

// ---------------- fused policy-softmax attention (no-max, 12 waves) --------
// r14-proven version, byte-identical. ONE block per (b,h): grid 384, 768
// threads = 12 waves. Q/K/V staged once into swizzled LDS (145.5 KB, 1
// block/CU); each wave handles 2 of the 24 query-groups. No-max softmax;
// policy mask pre-packed into 3 u32. (r12/r15's global-K variant compiles to
// a 44-VGPR zero-ILP kernel regardless of launch bounds -- abandoned.)
__global__ __launch_bounds__(768, 1) void attn_kernel(
    const __bf16* __restrict__ qkbuf, const __bf16* __restrict__ vtbuf,
    const float* __restrict__ policy, __bf16* __restrict__ attb) {
    __shared__ __bf16 Qlds[NN * HD];  // [row][128B], swz: byte ^= (row&7)<<4
    __shared__ __bf16 Klds[NN * HD];
    __shared__ __bf16 Vlds[HD * NN];  // [row][768B], swz on 16B chunks
    __shared__ float pol[NN];

    const int tid = threadIdx.x;
    const int l = tid & 63;
    const int w = tid >> 6;           // 0..11
    const int g = l >> 4, q16 = l & 15;
    const int bh = blockIdx.x;
    const int b = bh / HH, h = bh % HH;

    // Q/K stage: 3072 chunks each, 4 issues per thread
    const __bf16* qg = qkbuf + (size_t)b * NN * 1536 + h * HD;
    const __bf16* kg = qg + CC;
#pragma unroll
    for (int p = 0; p < 4; ++p) {
        const int cs = p * 768 + w * 64 + l;
        const int row = cs >> 3, cin = cs & 7;
        const size_t go = (size_t)row * 1536 + (size_t)((cin ^ (row & 7)) << 3);
        gload_lds16(&qg[go], &Qlds[(p * 768 + w * 64) * 8]);
        gload_lds16(&kg[go], &Klds[(p * 768 + w * 64) * 8]);
    }
    const __bf16* vg = vtbuf + (size_t)(b * HH + h) * HD * NN;
#pragma unroll
    for (int p = 0; p < 4; ++p) {
        const int cs = p * 768 + w * 64 + l;
        const int row = cs / 48, cin = cs - row * 48;
        gload_lds16(&vg[row * NN + ((cin ^ (row & 7)) << 3)], &Vlds[(p * 768 + w * 64) * 8]);
    }
    for (int i = tid; i < NN; i += 768) pol[i] = policy[b * NN + i];
    __syncthreads();

    const int sw = (q16 & 7) << 4;

    // pack this thread's 96 policy-keep bits (key = kt*64 + t*16 + g*4 + r,
    // bit = kt*16 + t*4 + r) into 3 u32 -- built once, reused both passes.
    unsigned kw0 = 0, kw1 = 0, kw2 = 0;
#pragma unroll
    for (int kt = 0; kt < 6; ++kt)
#pragma unroll
        for (int t = 0; t < 4; ++t)
#pragma unroll
            for (int r = 0; r < 4; ++r) {
                const int key = kt * 64 + t * 16 + g * 4 + r;
                const unsigned bset = (pol[key] > 0.5f) ? 1u : 0u;
                const int bit = kt * 16 + t * 4 + r;
                if (bit < 32) kw0 |= bset << bit;
                else if (bit < 64) kw1 |= bset << (bit - 32);
                else kw2 |= bset << (bit - 64);
            }

#pragma unroll 1
    for (int ps = 0; ps < 2; ++ps) {
        const int qrow = (ps * 12 + w) * 16 + q16;  // 24 query-groups over 12 waves
        const int qbyte0 = qrow * 128 + g * 16;
        const bf16x8 qf0 = *(const bf16x8*)((const char*)Qlds + (qbyte0 ^ sw));
        const bf16x8 qf1 = *(const bf16x8*)((const char*)Qlds + ((qbyte0 + 64) ^ sw));

        // per-pass mask: OR in the self-key bit (eye blend) if this thread owns it
        unsigned pw0 = kw0, pw1 = kw1, pw2 = kw2;
        if (((qrow >> 2) & 3) == g) {
            const int sbit = (qrow >> 6) * 16 + ((qrow >> 4) & 3) * 4 + (qrow & 3);
            if (sbit < 32) pw0 |= 1u << sbit;
            else if (sbit < 64) pw1 |= 1u << (sbit - 32);
            else pw2 |= 1u << (sbit - 64);
        }

        f32x4 oacc[4] = {};
        f32x4 ssum = {0.f, 0.f, 0.f, 0.f};

#pragma unroll 2
        for (int kt = 0; kt < 6; ++kt) {
            f32x4 st[4];
            __builtin_amdgcn_s_setprio(1);
#pragma unroll
            for (int t = 0; t < 4; ++t) {
                const int byte0 = ((kt * 4 + t) * 16 + q16) * 128 + g * 16;
                bf16x8 k0 = *(const bf16x8*)((const char*)Klds + (byte0 ^ sw));
                bf16x8 k1 = *(const bf16x8*)((const char*)Klds + ((byte0 + 64) ^ sw));
                f32x4 z = {0.f, 0.f, 0.f, 0.f};
                st[t] = mfma16(k1, qf1, mfma16(k0, qf0, z));
            }
            __builtin_amdgcn_s_setprio(0);

            // e = keep ? exp(s) : 0  (no max subtraction; |s| <= ~2)
#pragma unroll
            for (int t = 0; t < 4; ++t) {
#pragma unroll
                for (int r = 0; r < 4; ++r) {
                    const int bit = kt * 16 + t * 4 + r;  // compile-time
                    const unsigned wsel = (bit < 32) ? pw0 : ((bit < 64) ? pw1 : pw2);
                    const bool keep = (wsel >> (bit & 31)) & 1u;
                    st[t][r] = keep ? __expf(st[t][r]) : 0.f;
                }
                ssum += st[t];
            }

            __builtin_amdgcn_s_setprio(1);
#pragma unroll
            for (int c4 = 0; c4 < 2; ++c4) {
                bf16x8 pf;
#pragma unroll
                for (int r = 0; r < 4; ++r) {
                    pf[r] = (__bf16)st[2 * c4][r];
                    pf[r + 4] = (__bf16)st[2 * c4 + 1][r];
                }
                const int c = kt * 2 + c4;
#pragma unroll
                for (int db = 0; db < 4; ++db) {
                    const int byte0 = (db * 16 + q16) * 768 + c * 64 + g * 8;
                    bf16x4 v0 = *(const bf16x4*)((const char*)Vlds + (byte0 ^ sw));
                    bf16x4 v1 = *(const bf16x4*)((const char*)Vlds + ((byte0 + 32) ^ sw));
                    bf16x8 vf;
#pragma unroll
                    for (int r = 0; r < 4; ++r) { vf[r] = v0[r]; vf[r + 4] = v1[r]; }
                    oacc[db] = mfma16(vf, pf, oacc[db]);
                }
            }
            __builtin_amdgcn_s_setprio(0);
        }

        float sum = (ssum[0] + ssum[1]) + (ssum[2] + ssum[3]);
        sum += __shfl_xor(sum, 16);
        sum += __shfl_xor(sum, 32);
        const float dinv = 1.f / (sum + 1e-6f);  // eps terms ~1e-6 rel: negligible

        __bf16* op = attb + ((size_t)b * NN + qrow) * CC + h * HD;
#pragma unroll
        for (int db = 0; db < 4; ++db) {
            bf16x4 pk;
#pragma unroll
            for (int r = 0; r < 4; ++r) pk[r] = (__bf16)(oacc[db][r] * dinv);
            *(bf16x4*)&op[db * 16 + g * 4] = pk;
        }
    }
}

extern "C" void kernel_launch(void* const* d_in, const int* in_sizes, int n_in,
                              void* d_out, int out_size, void* d_ws, size_t ws_size,
                              hipStream_t stream) {
    (void)in_sizes; (void)n_in; (void)out_size; (void)ws_size;
    const float* x      = (const float*)d_in[0];
    const float* policy = (const float*)d_in[1];
    const float* qkv_w  = (const float*)d_in[2];
    const float* qkv_b  = (const float*)d_in[3];
    const float* proj_w = (const float*)d_in[4];
    const float* proj_b = (const float*)d_in[5];
    float* out = (float*)d_out;

    // workspace layout (bf16), total ~94.5 MB
    __bf16* xb    = (__bf16*)d_ws;                     // 12288*768
    __bf16* wqkv  = xb + (size_t)12288 * 768;          // 2304*768
    __bf16* wproj = wqkv + (size_t)2304 * 768;         // 768*768
    __bf16* qkbuf = wproj + (size_t)768 * 768;         // 12288*1536 (Q|K)
    __bf16* vtbuf = qkbuf + (size_t)12288 * 1536;      // 32*12*64*384 (V^T)
    __bf16* attb  = vtbuf + (size_t)BB * HH * HD * NN; // 12288*768

    const int units = XU + QKVU + PU;
    cvt_kernel<<<(units + 255) / 256, 256, 0, stream>>>(x, qkv_w, proj_w, xb);

    gemm_kernel<0><<<dim3(96, 18), 256, 0, stream>>>(xb, wqkv, qkv_b, qkbuf, vtbuf, nullptr);
    attn_kernel<<<384, 768, 0, stream>>>(qkbuf, vtbuf, policy, attb);
    gemm_kernel<1><<<dim3(96, 6), 256, 0, stream>>>(attb, wproj, proj_b, nullptr, nullptr, out);
}

// Round 17
// 139.049 us; speedup vs baseline: 1.2147x; 1.0856x over previous
//
#include <hip/hip_runtime.h>

// Problem: B=32, N=384, C=768, H=12, hd=64, scale=1/8, EPS=1e-6
#define BB 32
#define NN 384
#define CC 768
#define HH 12
#define HD 64

typedef __attribute__((ext_vector_type(4))) float f32x4;
typedef __attribute__((ext_vector_type(8))) __bf16 bf16x8;
typedef __attribute__((ext_vector_type(4))) __bf16 bf16x4;

static __device__ __forceinline__ f32x4 mfma16(bf16x8 a, bf16x8 b, f32x4 c) {
    return __builtin_amdgcn_mfma_f32_16x16x32_bf16(a, b, c, 0, 0, 0);
}

// async global->LDS DMA, 16B per lane. LDS dest is WAVE-UNIFORM base; HW adds lane*16.
static __device__ __forceinline__ void gload_lds16(const void* g, void* l) {
    __builtin_amdgcn_global_load_lds((const __attribute__((address_space(1))) void*)g,
                                     (__attribute__((address_space(3))) void*)l, 16, 0, 0);
}

// ---------------- fused f32 -> bf16 convert (all 3 sources, 1 launch) ------
#define XU   1179648   // x units (of 8 elem)
#define QU   73728     // qkv_w Q-part units
#define QKVU 221184    // qkv_w total units
#define PU   73728     // proj_w units
__global__ void cvt_kernel(const float* __restrict__ x, const float* __restrict__ qkv_w,
                           const float* __restrict__ proj_w, __bf16* __restrict__ dst) {
    const int i = blockIdx.x * blockDim.x + threadIdx.x;
    if (i >= XU + QKVU + PU) return;
    const float* src;
    float sc = 1.f;
    if (i < XU) src = x + (size_t)i * 8;
    else if (i < XU + QKVU) {
        src = qkv_w + (size_t)(i - XU) * 8;
        if (i < XU + QU) sc = 0.125f;  // Q weight rows pre-scaled by softmax scale
    } else src = proj_w + (size_t)(i - XU - QKVU) * 8;
    f32x4 a = *(const f32x4*)src;
    f32x4 b = *(const f32x4*)(src + 4);
    bf16x8 o;
#pragma unroll
    for (int j = 0; j < 4; ++j) { o[j] = (__bf16)(a[j] * sc); o[j + 4] = (__bf16)(b[j] * sc); }
    *(bf16x8*)(dst + (size_t)i * 8) = o;
}

// ---------------- GEMM: C[M][ncol] = A[M][768] * Bw[ncol][768]^T + bias ----
// r14-proven (60us/725TF): 2-phase dbuf + both-sides XOR swizzle (conflicts=0),
// single __syncthreads per K-step. r16's manual vmcnt(8)/double-barrier split
// REGRESSED (68us: sched_barrier pins defeated compiler scheduling, m141-mode)
// -- reverted.
template <int EPI>
__global__ __launch_bounds__(256, 2) void gemm_kernel(
    const __bf16* __restrict__ A, const __bf16* __restrict__ Bw,
    const float* __restrict__ bias,
    __bf16* __restrict__ qkbuf, __bf16* __restrict__ vtbuf,
    float* __restrict__ fout) {
    __shared__ __bf16 SA[2][128 * 64];
    __shared__ __bf16 SB[2][128 * 64];

    const int tid = threadIdx.x;
    const int l = tid & 63;
    const int w = tid >> 6;
    const int g = l >> 4, q16 = l & 15;
    const int mb = blockIdx.x * 128;
    const int nb = blockIdx.y * 128;
    const int wrb = (w >> 1) * 64;
    const int wcb = (w & 1) * 64;
    const int swz = q16 & 7;  // frag-row & 7 == q16 & 7 (row bases are mult of 16)

    auto stage = [&](int buf, int kt) {
#pragma unroll
        for (int j = 0; j < 4; ++j) {
            const int ci = j * 256 + w * 64 + l;
            const int row = ci >> 3, c = ci & 7;
            const size_t go = (size_t)row * CC + kt * 64 + ((c ^ (row & 7)) << 3);
            gload_lds16(&A[(size_t)mb * CC + go], &SA[buf][(j * 256 + w * 64) * 8]);
            gload_lds16(&Bw[(size_t)nb * CC + go], &SB[buf][(j * 256 + w * 64) * 8]);
        }
    };

    f32x4 acc[4][4] = {};

    stage(0, 0);
    __syncthreads();  // tile 0 landed

    for (int kt = 0; kt < 12; ++kt) {
        const int buf = kt & 1;
        if (kt < 11) stage(buf ^ 1, kt + 1);  // prefetch overlaps compute below
        const char* pa = (const char*)&SA[buf][0];
        const char* pb = (const char*)&SB[buf][0];
#pragma unroll
        for (int c4 = 0; c4 < 2; ++c4) {
            bf16x8 af[4], bfr[4];
#pragma unroll
            for (int m = 0; m < 4; ++m)
                af[m] = *(const bf16x8*)(pa + (wrb + m * 16 + q16) * 128 +
                                         (((c4 * 4 + g) ^ swz) << 4));
#pragma unroll
            for (int n = 0; n < 4; ++n)
                bfr[n] = *(const bf16x8*)(pb + (wcb + n * 16 + q16) * 128 +
                                          (((c4 * 4 + g) ^ swz) << 4));
            __builtin_amdgcn_s_setprio(1);
#pragma unroll
            for (int m = 0; m < 4; ++m)
#pragma unroll
                for (int n = 0; n < 4; ++n)
                    acc[m][n] = mfma16(af[m], bfr[n], acc[m][n]);
            __builtin_amdgcn_s_setprio(0);
        }
        __syncthreads();  // drains prefetch (vmcnt) + reads (lgkm)
    }

    // epilogue. C/D layout: col = q16 (+16*n), row = 4*g + r (+16*m)
    if constexpr (EPI == 0) {
        const int bbatch = mb / NN;
        const int tokb = mb % NN;
#pragma unroll
        for (int n = 0; n < 4; ++n) {
            const int colb = nb + wcb + n * 16;
            const int col = colb + q16;
            float bs = bias[col];
            if (colb < 2 * CC) {
                if (colb < CC) bs *= 0.125f;
#pragma unroll
                for (int m = 0; m < 4; ++m) {
                    const int row = mb + wrb + m * 16 + g * 4;
#pragma unroll
                    for (int r = 0; r < 4; ++r)
                        qkbuf[(size_t)(row + r) * 1536 + col] = (__bf16)(acc[m][n][r] + bs);
                }
            } else {
                const int dd = (col - 2 * CC) & 63;
                const int hh = (colb - 2 * CC) >> 6;
                __bf16* vp = vtbuf + ((size_t)(bbatch * HH + hh) * HD + dd) * NN;
#pragma unroll
                for (int m = 0; m < 4; ++m) {
                    const int tok = tokb + wrb + m * 16 + g * 4;
                    bf16x4 pk;
#pragma unroll
                    for (int r = 0; r < 4; ++r) pk[r] = (__bf16)(acc[m][n][r] + bs);
                    *(bf16x4*)&vp[tok] = pk;
                }
            }
        }
    } else {
#pragma unroll
        for (int n = 0; n < 4; ++n) {
            const int col = nb + wcb + n * 16 + q16;
            const float bs = bias[col];
#pragma unroll
            for (int m = 0; m < 4; ++m)
#pragma unroll
                for (int r = 0; r < 4; ++r)
                    fout[(size_t)(mb + wrb + m * 16 + g * 4 + r) * CC + col] = acc[m][n][r] + bs;
        }
    }
}

// ---------------- fused policy-softmax attention (no-max, 12 waves) --------
// r14 base. ONE block per (b,h): grid 384, 768 threads = 12 waves. Q/K/V in
// swizzled LDS (145.5 KB, 1 block/CU); no-max softmax; mask in 3 u32.
// NEW: V staging DEFERRED past the first barrier -- its 48 KB lands while
// mask-packing + pass-0 QK/exp run; a one-time {vmcnt(0); s_barrier} before
// the FIRST PV (uniform ps==0&&kt==0 branch, hit exactly once by all threads)
// makes Vlds visible before any read.
__global__ __launch_bounds__(768, 1) void attn_kernel(
    const __bf16* __restrict__ qkbuf, const __bf16* __restrict__ vtbuf,
    const float* __restrict__ policy, __bf16* __restrict__ attb) {
    __shared__ __bf16 Qlds[NN * HD];  // [row][128B], swz: byte ^= (row&7)<<4
    __shared__ __bf16 Klds[NN * HD];
    __shared__ __bf16 Vlds[HD * NN];  // [row][768B], swz on 16B chunks
    __shared__ float pol[NN];

    const int tid = threadIdx.x;
    const int l = tid & 63;
    const int w = tid >> 6;           // 0..11
    const int g = l >> 4, q16 = l & 15;
    const int bh = blockIdx.x;
    const int b = bh / HH, h = bh % HH;

    // Q/K stage first (8 issues/thread); V deferred past the barrier
    const __bf16* qg = qkbuf + (size_t)b * NN * 1536 + h * HD;
    const __bf16* kg = qg + CC;
#pragma unroll
    for (int p = 0; p < 4; ++p) {
        const int cs = p * 768 + w * 64 + l;
        const int row = cs >> 3, cin = cs & 7;
        const size_t go = (size_t)row * 1536 + (size_t)((cin ^ (row & 7)) << 3);
        gload_lds16(&qg[go], &Qlds[(p * 768 + w * 64) * 8]);
        gload_lds16(&kg[go], &Klds[(p * 768 + w * 64) * 8]);
    }
    for (int i = tid; i < NN; i += 768) pol[i] = policy[b * NN + i];
    __syncthreads();  // Q, K, pol ready (V not yet issued)

    // V stage now -- in flight under mask packing + pass-0 QK/exp
    const __bf16* vg = vtbuf + (size_t)(b * HH + h) * HD * NN;
#pragma unroll
    for (int p = 0; p < 4; ++p) {
        const int cs = p * 768 + w * 64 + l;
        const int row = cs / 48, cin = cs - row * 48;
        gload_lds16(&vg[row * NN + ((cin ^ (row & 7)) << 3)], &Vlds[(p * 768 + w * 64) * 8]);
    }

    const int sw = (q16 & 7) << 4;

    // pack this thread's 96 policy-keep bits (key = kt*64 + t*16 + g*4 + r,
    // bit = kt*16 + t*4 + r) into 3 u32 -- built once, reused both passes.
    unsigned kw0 = 0, kw1 = 0, kw2 = 0;
#pragma unroll
    for (int kt = 0; kt < 6; ++kt)
#pragma unroll
        for (int t = 0; t < 4; ++t)
#pragma unroll
            for (int r = 0; r < 4; ++r) {
                const int key = kt * 64 + t * 16 + g * 4 + r;
                const unsigned bset = (pol[key] > 0.5f) ? 1u : 0u;
                const int bit = kt * 16 + t * 4 + r;
                if (bit < 32) kw0 |= bset << bit;
                else if (bit < 64) kw1 |= bset << (bit - 32);
                else kw2 |= bset << (bit - 64);
            }

#pragma unroll 1
    for (int ps = 0; ps < 2; ++ps) {
        const int qrow = (ps * 12 + w) * 16 + q16;  // 24 query-groups over 12 waves
        const int qbyte0 = qrow * 128 + g * 16;
        const bf16x8 qf0 = *(const bf16x8*)((const char*)Qlds + (qbyte0 ^ sw));
        const bf16x8 qf1 = *(const bf16x8*)((const char*)Qlds + ((qbyte0 + 64) ^ sw));

        // per-pass mask: OR in the self-key bit (eye blend) if this thread owns it
        unsigned pw0 = kw0, pw1 = kw1, pw2 = kw2;
        if (((qrow >> 2) & 3) == g) {
            const int sbit = (qrow >> 6) * 16 + ((qrow >> 4) & 3) * 4 + (qrow & 3);
            if (sbit < 32) pw0 |= 1u << sbit;
            else if (sbit < 64) pw1 |= 1u << (sbit - 32);
            else pw2 |= 1u << (sbit - 64);
        }

        f32x4 oacc[4] = {};
        f32x4 ssum = {0.f, 0.f, 0.f, 0.f};

#pragma unroll 2
        for (int kt = 0; kt < 6; ++kt) {
            f32x4 st[4];
            __builtin_amdgcn_s_setprio(1);
#pragma unroll
            for (int t = 0; t < 4; ++t) {
                const int byte0 = ((kt * 4 + t) * 16 + q16) * 128 + g * 16;
                bf16x8 k0 = *(const bf16x8*)((const char*)Klds + (byte0 ^ sw));
                bf16x8 k1 = *(const bf16x8*)((const char*)Klds + ((byte0 + 64) ^ sw));
                f32x4 z = {0.f, 0.f, 0.f, 0.f};
                st[t] = mfma16(k1, qf1, mfma16(k0, qf0, z));
            }
            __builtin_amdgcn_s_setprio(0);

            // e = keep ? exp(s) : 0  (no max subtraction; |s| <= ~2)
#pragma unroll
            for (int t = 0; t < 4; ++t) {
#pragma unroll
                for (int r = 0; r < 4; ++r) {
                    const int bit = kt * 16 + t * 4 + r;  // compile-time
                    const unsigned wsel = (bit < 32) ? pw0 : ((bit < 64) ? pw1 : pw2);
                    const bool keep = (wsel >> (bit & 31)) & 1u;
                    st[t][r] = keep ? __expf(st[t][r]) : 0.f;
                }
                ssum += st[t];
            }

            // one-time V-visibility rendezvous, just before the first PV use.
            // Uniform branch (all 768 threads, exactly once) -> legal barrier.
            if (ps == 0 && kt == 0) {
                asm volatile("s_waitcnt vmcnt(0)" ::: "memory");
                __builtin_amdgcn_sched_barrier(0);
                asm volatile("s_barrier" ::: "memory");
            }

            __builtin_amdgcn_s_setprio(1);
#pragma unroll
            for (int c4 = 0; c4 < 2; ++c4) {
                bf16x8 pf;
#pragma unroll
                for (int r = 0; r < 4; ++r) {
                    pf[r] = (__bf16)st[2 * c4][r];
                    pf[r + 4] = (__bf16)st[2 * c4 + 1][r];
                }
                const int c = kt * 2 + c4;
#pragma unroll
                for (int db = 0; db < 4; ++db) {
                    const int byte0 = (db * 16 + q16) * 768 + c * 64 + g * 8;
                    bf16x4 v0 = *(const bf16x4*)((const char*)Vlds + (byte0 ^ sw));
                    bf16x4 v1 = *(const bf16x4*)((const char*)Vlds + ((byte0 + 32) ^ sw));
                    bf16x8 vf;
#pragma unroll
                    for (int r = 0; r < 4; ++r) { vf[r] = v0[r]; vf[r + 4] = v1[r]; }
                    oacc[db] = mfma16(vf, pf, oacc[db]);
                }
            }
            __builtin_amdgcn_s_setprio(0);
        }

        float sum = (ssum[0] + ssum[1]) + (ssum[2] + ssum[3]);
        sum += __shfl_xor(sum, 16);
        sum += __shfl_xor(sum, 32);
        const float dinv = 1.f / (sum + 1e-6f);  // eps terms ~1e-6 rel: negligible

        __bf16* op = attb + ((size_t)b * NN + qrow) * CC + h * HD;
#pragma unroll
        for (int db = 0; db < 4; ++db) {
            bf16x4 pk;
#pragma unroll
            for (int r = 0; r < 4; ++r) pk[r] = (__bf16)(oacc[db][r] * dinv);
            *(bf16x4*)&op[db * 16 + g * 4] = pk;
        }
    }
}

extern "C" void kernel_launch(void* const* d_in, const int* in_sizes, int n_in,
                              void* d_out, int out_size, void* d_ws, size_t ws_size,
                              hipStream_t stream) {
    (void)in_sizes; (void)n_in; (void)out_size; (void)ws_size;
    const float* x      = (const float*)d_in[0];
    const float* policy = (const float*)d_in[1];
    const float* qkv_w  = (const float*)d_in[2];
    const float* qkv_b  = (const float*)d_in[3];
    const float* proj_w = (const float*)d_in[4];
    const float* proj_b = (const float*)d_in[5];
    float* out = (float*)d_out;

    // workspace layout (bf16), total ~94.5 MB
    __bf16* xb    = (__bf16*)d_ws;                     // 12288*768
    __bf16* wqkv  = xb + (size_t)12288 * 768;          // 2304*768
    __bf16* wproj = wqkv + (size_t)2304 * 768;         // 768*768
    __bf16* qkbuf = wproj + (size_t)768 * 768;         // 12288*1536 (Q|K)
    __bf16* vtbuf = qkbuf + (size_t)12288 * 1536;      // 32*12*64*384 (V^T)
    __bf16* attb  = vtbuf + (size_t)BB * HH * HD * NN; // 12288*768

    const int units = XU + QKVU + PU;
    cvt_kernel<<<(units + 255) / 256, 256, 0, stream>>>(x, qkv_w, proj_w, xb);

    gemm_kernel<0><<<dim3(96, 18), 256, 0, stream>>>(xb, wqkv, qkv_b, qkbuf, vtbuf, nullptr);
    attn_kernel<<<384, 768, 0, stream>>>(qkbuf, vtbuf, policy, attb);
    gemm_kernel<1><<<dim3(96, 6), 256, 0, stream>>>(attb, wproj, proj_b, nullptr, nullptr, out);
}

// Round 18
// 138.333 us; speedup vs baseline: 1.2210x; 1.0052x over previous
//
#include <hip/hip_runtime.h>

// Problem: B=32, N=384, C=768, H=12, hd=64, scale=1/8, EPS=1e-6
#define BB 32
#define NN 384
#define CC 768
#define HH 12
#define HD 64

typedef __attribute__((ext_vector_type(4))) float f32x4;
typedef __attribute__((ext_vector_type(8))) __bf16 bf16x8;
typedef __attribute__((ext_vector_type(4))) __bf16 bf16x4;

static __device__ __forceinline__ f32x4 mfma16(bf16x8 a, bf16x8 b, f32x4 c) {
    return __builtin_amdgcn_mfma_f32_16x16x32_bf16(a, b, c, 0, 0, 0);
}

// async global->LDS DMA, 16B per lane. LDS dest is WAVE-UNIFORM base; HW adds lane*16.
static __device__ __forceinline__ void gload_lds16(const void* g, void* l) {
    __builtin_amdgcn_global_load_lds((const __attribute__((address_space(1))) void*)g,
                                     (__attribute__((address_space(3))) void*)l, 16, 0, 0);
}

// ---------------- fused f32 -> bf16 convert (all 3 sources, 1 launch) ------
#define XU   1179648   // x units (of 8 elem)
#define QU   73728     // qkv_w Q-part units
#define QKVU 221184    // qkv_w total units
#define PU   73728     // proj_w units
__global__ void cvt_kernel(const float* __restrict__ x, const float* __restrict__ qkv_w,
                           const float* __restrict__ proj_w, __bf16* __restrict__ dst) {
    const int i = blockIdx.x * blockDim.x + threadIdx.x;
    if (i >= XU + QKVU + PU) return;
    const float* src;
    float sc = 1.f;
    if (i < XU) src = x + (size_t)i * 8;
    else if (i < XU + QKVU) {
        src = qkv_w + (size_t)(i - XU) * 8;
        if (i < XU + QU) sc = 0.125f;  // Q weight rows pre-scaled by softmax scale
    } else src = proj_w + (size_t)(i - XU - QKVU) * 8;
    f32x4 a = *(const f32x4*)src;
    f32x4 b = *(const f32x4*)(src + 4);
    bf16x8 o;
#pragma unroll
    for (int j = 0; j < 4; ++j) { o[j] = (__bf16)(a[j] * sc); o[j + 4] = (__bf16)(b[j] * sc); }
    *(bf16x8*)(dst + (size_t)i * 8) = o;
}

// ---------------- GEMM: C[M][ncol] = A[M][768] * Bw[ncol][768]^T + bias ----
// r14-proven (60us/725TF): 2-phase dbuf + both-sides XOR swizzle (conflicts=0),
// single __syncthreads per K-step.
template <int EPI>
__global__ __launch_bounds__(256, 2) void gemm_kernel(
    const __bf16* __restrict__ A, const __bf16* __restrict__ Bw,
    const float* __restrict__ bias,
    __bf16* __restrict__ qkbuf, __bf16* __restrict__ vtbuf,
    float* __restrict__ fout) {
    __shared__ __bf16 SA[2][128 * 64];
    __shared__ __bf16 SB[2][128 * 64];

    const int tid = threadIdx.x;
    const int l = tid & 63;
    const int w = tid >> 6;
    const int g = l >> 4, q16 = l & 15;
    const int mb = blockIdx.x * 128;
    const int nb = blockIdx.y * 128;
    const int wrb = (w >> 1) * 64;
    const int wcb = (w & 1) * 64;
    const int swz = q16 & 7;  // frag-row & 7 == q16 & 7 (row bases are mult of 16)

    auto stage = [&](int buf, int kt) {
#pragma unroll
        for (int j = 0; j < 4; ++j) {
            const int ci = j * 256 + w * 64 + l;
            const int row = ci >> 3, c = ci & 7;
            const size_t go = (size_t)row * CC + kt * 64 + ((c ^ (row & 7)) << 3);
            gload_lds16(&A[(size_t)mb * CC + go], &SA[buf][(j * 256 + w * 64) * 8]);
            gload_lds16(&Bw[(size_t)nb * CC + go], &SB[buf][(j * 256 + w * 64) * 8]);
        }
    };

    f32x4 acc[4][4] = {};

    stage(0, 0);
    __syncthreads();  // tile 0 landed

    for (int kt = 0; kt < 12; ++kt) {
        const int buf = kt & 1;
        if (kt < 11) stage(buf ^ 1, kt + 1);  // prefetch overlaps compute below
        const char* pa = (const char*)&SA[buf][0];
        const char* pb = (const char*)&SB[buf][0];
#pragma unroll
        for (int c4 = 0; c4 < 2; ++c4) {
            bf16x8 af[4], bfr[4];
#pragma unroll
            for (int m = 0; m < 4; ++m)
                af[m] = *(const bf16x8*)(pa + (wrb + m * 16 + q16) * 128 +
                                         (((c4 * 4 + g) ^ swz) << 4));
#pragma unroll
            for (int n = 0; n < 4; ++n)
                bfr[n] = *(const bf16x8*)(pb + (wcb + n * 16 + q16) * 128 +
                                          (((c4 * 4 + g) ^ swz) << 4));
            __builtin_amdgcn_s_setprio(1);
#pragma unroll
            for (int m = 0; m < 4; ++m)
#pragma unroll
                for (int n = 0; n < 4; ++n)
                    acc[m][n] = mfma16(af[m], bfr[n], acc[m][n]);
            __builtin_amdgcn_s_setprio(0);
        }
        __syncthreads();  // drains prefetch (vmcnt) + reads (lgkm)
    }

    // epilogue. C/D layout: col = q16 (+16*n), row = 4*g + r (+16*m)
    if constexpr (EPI == 0) {
        const int bbatch = mb / NN;
        const int tokb = mb % NN;
#pragma unroll
        for (int n = 0; n < 4; ++n) {
            const int colb = nb + wcb + n * 16;
            const int col = colb + q16;
            float bs = bias[col];
            if (colb < 2 * CC) {
                if (colb < CC) bs *= 0.125f;
#pragma unroll
                for (int m = 0; m < 4; ++m) {
                    const int row = mb + wrb + m * 16 + g * 4;
#pragma unroll
                    for (int r = 0; r < 4; ++r)
                        qkbuf[(size_t)(row + r) * 1536 + col] = (__bf16)(acc[m][n][r] + bs);
                }
            } else {
                const int dd = (col - 2 * CC) & 63;
                const int hh = (colb - 2 * CC) >> 6;
                __bf16* vp = vtbuf + ((size_t)(bbatch * HH + hh) * HD + dd) * NN;
#pragma unroll
                for (int m = 0; m < 4; ++m) {
                    const int tok = tokb + wrb + m * 16 + g * 4;
                    bf16x4 pk;
#pragma unroll
                    for (int r = 0; r < 4; ++r) pk[r] = (__bf16)(acc[m][n][r] + bs);
                    *(bf16x4*)&vp[tok] = pk;
                }
            }
        }
    } else {
#pragma unroll
        for (int n = 0; n < 4; ++n) {
            const int col = nb + wcb + n * 16 + q16;
            const float bs = bias[col];
#pragma unroll
            for (int m = 0; m < 4; ++m)
#pragma unroll
                for (int r = 0; r < 4; ++r)
                    fout[(size_t)(mb + wrb + m * 16 + g * 4 + r) * CC + col] = acc[m][n][r] + bs;
        }
    }
}

// ---------------- fused policy-softmax attention (no-max, 12 waves) --------
// r17 base (V-deferred staging). NEW: all 16 V-fragment ds_reads of each kt
// HOISTED before the exp/mask phase (named vv0/vv1, static indices) -- the
// ~100cy of independent exp VALU hides the LDS-read latency that dominated
// (MfmaUtil 7%, VALUBusy 23%: stall-bound). +32 VGPR transient, ~92 hot.
__global__ __launch_bounds__(768, 1) void attn_kernel(
    const __bf16* __restrict__ qkbuf, const __bf16* __restrict__ vtbuf,
    const float* __restrict__ policy, __bf16* __restrict__ attb) {
    __shared__ __bf16 Qlds[NN * HD];  // [row][128B], swz: byte ^= (row&7)<<4
    __shared__ __bf16 Klds[NN * HD];
    __shared__ __bf16 Vlds[HD * NN];  // [row][768B], swz on 16B chunks
    __shared__ float pol[NN];

    const int tid = threadIdx.x;
    const int l = tid & 63;
    const int w = tid >> 6;           // 0..11
    const int g = l >> 4, q16 = l & 15;
    const int bh = blockIdx.x;
    const int b = bh / HH, h = bh % HH;

    // Q/K stage first (8 issues/thread); V deferred past the barrier
    const __bf16* qg = qkbuf + (size_t)b * NN * 1536 + h * HD;
    const __bf16* kg = qg + CC;
#pragma unroll
    for (int p = 0; p < 4; ++p) {
        const int cs = p * 768 + w * 64 + l;
        const int row = cs >> 3, cin = cs & 7;
        const size_t go = (size_t)row * 1536 + (size_t)((cin ^ (row & 7)) << 3);
        gload_lds16(&qg[go], &Qlds[(p * 768 + w * 64) * 8]);
        gload_lds16(&kg[go], &Klds[(p * 768 + w * 64) * 8]);
    }
    for (int i = tid; i < NN; i += 768) pol[i] = policy[b * NN + i];
    __syncthreads();  // Q, K, pol ready (V not yet issued)

    // V stage now -- in flight under mask packing + pass-0 QK
    const __bf16* vg = vtbuf + (size_t)(b * HH + h) * HD * NN;
#pragma unroll
    for (int p = 0; p < 4; ++p) {
        const int cs = p * 768 + w * 64 + l;
        const int row = cs / 48, cin = cs - row * 48;
        gload_lds16(&vg[row * NN + ((cin ^ (row & 7)) << 3)], &Vlds[(p * 768 + w * 64) * 8]);
    }

    const int sw = (q16 & 7) << 4;

    // pack this thread's 96 policy-keep bits (key = kt*64 + t*16 + g*4 + r,
    // bit = kt*16 + t*4 + r) into 3 u32 -- built once, reused both passes.
    unsigned kw0 = 0, kw1 = 0, kw2 = 0;
#pragma unroll
    for (int kt = 0; kt < 6; ++kt)
#pragma unroll
        for (int t = 0; t < 4; ++t)
#pragma unroll
            for (int r = 0; r < 4; ++r) {
                const int key = kt * 64 + t * 16 + g * 4 + r;
                const unsigned bset = (pol[key] > 0.5f) ? 1u : 0u;
                const int bit = kt * 16 + t * 4 + r;
                if (bit < 32) kw0 |= bset << bit;
                else if (bit < 64) kw1 |= bset << (bit - 32);
                else kw2 |= bset << (bit - 64);
            }

#pragma unroll 1
    for (int ps = 0; ps < 2; ++ps) {
        const int qrow = (ps * 12 + w) * 16 + q16;  // 24 query-groups over 12 waves
        const int qbyte0 = qrow * 128 + g * 16;
        const bf16x8 qf0 = *(const bf16x8*)((const char*)Qlds + (qbyte0 ^ sw));
        const bf16x8 qf1 = *(const bf16x8*)((const char*)Qlds + ((qbyte0 + 64) ^ sw));

        // per-pass mask: OR in the self-key bit (eye blend) if this thread owns it
        unsigned pw0 = kw0, pw1 = kw1, pw2 = kw2;
        if (((qrow >> 2) & 3) == g) {
            const int sbit = (qrow >> 6) * 16 + ((qrow >> 4) & 3) * 4 + (qrow & 3);
            if (sbit < 32) pw0 |= 1u << sbit;
            else if (sbit < 64) pw1 |= 1u << (sbit - 32);
            else pw2 |= 1u << (sbit - 64);
        }

        f32x4 oacc[4] = {};
        f32x4 ssum = {0.f, 0.f, 0.f, 0.f};

#pragma unroll 2
        for (int kt = 0; kt < 6; ++kt) {
            f32x4 st[4];
            __builtin_amdgcn_s_setprio(1);
#pragma unroll
            for (int t = 0; t < 4; ++t) {
                const int byte0 = ((kt * 4 + t) * 16 + q16) * 128 + g * 16;
                bf16x8 k0 = *(const bf16x8*)((const char*)Klds + (byte0 ^ sw));
                bf16x8 k1 = *(const bf16x8*)((const char*)Klds + ((byte0 + 64) ^ sw));
                f32x4 z = {0.f, 0.f, 0.f, 0.f};
                st[t] = mfma16(k1, qf1, mfma16(k0, qf0, z));
            }
            __builtin_amdgcn_s_setprio(0);

            // one-time V-visibility rendezvous, before the first hoisted V read.
            // Uniform branch (all 768 threads, exactly once) -> legal barrier.
            if (ps == 0 && kt == 0) {
                asm volatile("s_waitcnt vmcnt(0)" ::: "memory");
                __builtin_amdgcn_sched_barrier(0);
                asm volatile("s_barrier" ::: "memory");
            }

            // hoist ALL V fragments of this kt: ds latency hides under exp below
            bf16x4 vv0[2][4], vv1[2][4];  // static indices only (fully unrolled)
#pragma unroll
            for (int c4 = 0; c4 < 2; ++c4) {
                const int c = kt * 2 + c4;
#pragma unroll
                for (int db = 0; db < 4; ++db) {
                    const int byte0 = (db * 16 + q16) * 768 + c * 64 + g * 8;
                    vv0[c4][db] = *(const bf16x4*)((const char*)Vlds + (byte0 ^ sw));
                    vv1[c4][db] = *(const bf16x4*)((const char*)Vlds + ((byte0 + 32) ^ sw));
                }
            }

            // e = keep ? exp(s) : 0  (no max subtraction; |s| <= ~2)
#pragma unroll
            for (int t = 0; t < 4; ++t) {
#pragma unroll
                for (int r = 0; r < 4; ++r) {
                    const int bit = kt * 16 + t * 4 + r;  // compile-time
                    const unsigned wsel = (bit < 32) ? pw0 : ((bit < 64) ? pw1 : pw2);
                    const bool keep = (wsel >> (bit & 31)) & 1u;
                    st[t][r] = keep ? __expf(st[t][r]) : 0.f;
                }
                ssum += st[t];
            }

            __builtin_amdgcn_s_setprio(1);
#pragma unroll
            for (int c4 = 0; c4 < 2; ++c4) {
                bf16x8 pf;
#pragma unroll
                for (int r = 0; r < 4; ++r) {
                    pf[r] = (__bf16)st[2 * c4][r];
                    pf[r + 4] = (__bf16)st[2 * c4 + 1][r];
                }
#pragma unroll
                for (int db = 0; db < 4; ++db) {
                    bf16x8 vf;
#pragma unroll
                    for (int r = 0; r < 4; ++r) {
                        vf[r] = vv0[c4][db][r];
                        vf[r + 4] = vv1[c4][db][r];
                    }
                    oacc[db] = mfma16(vf, pf, oacc[db]);
                }
            }
            __builtin_amdgcn_s_setprio(0);
        }

        float sum = (ssum[0] + ssum[1]) + (ssum[2] + ssum[3]);
        sum += __shfl_xor(sum, 16);
        sum += __shfl_xor(sum, 32);
        const float dinv = 1.f / (sum + 1e-6f);  // eps terms ~1e-6 rel: negligible

        __bf16* op = attb + ((size_t)b * NN + qrow) * CC + h * HD;
#pragma unroll
        for (int db = 0; db < 4; ++db) {
            bf16x4 pk;
#pragma unroll
            for (int r = 0; r < 4; ++r) pk[r] = (__bf16)(oacc[db][r] * dinv);
            *(bf16x4*)&op[db * 16 + g * 4] = pk;
        }
    }
}

extern "C" void kernel_launch(void* const* d_in, const int* in_sizes, int n_in,
                              void* d_out, int out_size, void* d_ws, size_t ws_size,
                              hipStream_t stream) {
    (void)in_sizes; (void)n_in; (void)out_size; (void)ws_size;
    const float* x      = (const float*)d_in[0];
    const float* policy = (const float*)d_in[1];
    const float* qkv_w  = (const float*)d_in[2];
    const float* qkv_b  = (const float*)d_in[3];
    const float* proj_w = (const float*)d_in[4];
    const float* proj_b = (const float*)d_in[5];
    float* out = (float*)d_out;

    // workspace layout (bf16), total ~94.5 MB
    __bf16* xb    = (__bf16*)d_ws;                     // 12288*768
    __bf16* wqkv  = xb + (size_t)12288 * 768;          // 2304*768
    __bf16* wproj = wqkv + (size_t)2304 * 768;         // 768*768
    __bf16* qkbuf = wproj + (size_t)768 * 768;         // 12288*1536 (Q|K)
    __bf16* vtbuf = qkbuf + (size_t)12288 * 1536;      // 32*12*64*384 (V^T)
    __bf16* attb  = vtbuf + (size_t)BB * HH * HD * NN; // 12288*768

    const int units = XU + QKVU + PU;
    cvt_kernel<<<(units + 255) / 256, 256, 0, stream>>>(x, qkv_w, proj_w, xb);

    gemm_kernel<0><<<dim3(96, 18), 256, 0, stream>>>(xb, wqkv, qkv_b, qkbuf, vtbuf, nullptr);
    attn_kernel<<<384, 768, 0, stream>>>(qkbuf, vtbuf, policy, attb);
    gemm_kernel<1><<<dim3(96, 6), 256, 0, stream>>>(attb, wproj, proj_b, nullptr, nullptr, out);
}